// Round 1
// 121.677 us; speedup vs baseline: 1.0553x; 1.0553x over previous
//
#include <hip/hip_runtime.h>

// MetaUpSampler via bf16 MFMA — round 8 (= R7 + NHWC-bf16 pre-transpose).
// R7 counters: meta_up 45us, MfmaUtil 6.5%, VALUBusy 13%, HBM 13%, occ 31%
//   -> latency-bound. Staging gathers 64 channels/lane at 147KB stride as
//   4B fp32 loads + 64 f2bf per lane, only ~8 loads in flight -> ~8 serial
//   ~600cyc stalls per wave, and each row is re-staged 3x (tap overlap).
// R8 fix: one-shot NCHW-f32 -> NHWC-bf16 transpose (prep_kernel, fused with
//   the MLP stage; memory-bound ~12us). Main-kernel staging becomes 8x
//   contiguous 16B loads + 8 ds_writes per lane, zero conversions. The LDS
//   XOR swizzle is unchanged (moves into the source address).
// Workspace layout: lwb @ 0 (55KB), xt @ +64KB (18.9MB). ws_size is 256MB.

#define HH   192
#define WWD  192
#define SS   4
#define OC   3
#define PO   48
#define HID  256
#define W2LD 1728

typedef short  bf16x8 __attribute__((ext_vector_type(8)));
typedef float  f32x4  __attribute__((ext_vector_type(4)));

static __device__ __forceinline__ short f2bf(float f) {
    unsigned u = __float_as_uint(f);
    unsigned r = (u + 0x7fffu + ((u >> 16) & 1u)) >> 16;   // RNE
    return (short)r;
}

static __device__ __forceinline__ void pin(bf16x8& v) {
    asm volatile("" : "+v"(v));    // force VGPR residency; block load sinking
}

// ---------------- Stage A (fused): MLP -> weights  +  x -> NHWC bf16 -------
// Blocks 0..111: lw MLP (flattened (7,16) grid). Blocks 112..2415: transpose
// one (n,h,64w) tile of x from NCHW f32 to NHWC bf16 via an LDS tile.
__global__ __launch_bounds__(256) void prep_kernel(
        const float* __restrict__ x,
        const float* __restrict__ W1, const float* __restrict__ b1,
        const float* __restrict__ W2, const float* __restrict__ b2,
        short* __restrict__ lwb, short* __restrict__ xt) {
    const int b = blockIdx.x;
    const int t = threadIdx.x;
    if (b < 112) {
        __shared__ float hlds[HID];
        const int p = b / 7;
        {
            const float pi = (float)(p >> 2) * 0.25f;
            const float pj = (float)(p & 3) * 0.25f;
            const float v = 0.25f * W1[t] + pi * W1[HID + t] + pj * W1[2 * HID + t]
                          + b1[t];
            hlds[t] = v > 0.f ? v : 0.f;
        }
        __syncthreads();
        const int col = (b % 7) * 256 + t;   // 0..1791 (guard at 1728)
        if (col < W2LD) {
            float a = 0.f;
#pragma unroll 32
            for (int hh = 0; hh < HID; ++hh)
                a += hlds[hh] * W2[hh * W2LD + col];   // coalesced 4B + LDS bcast
            const int o = col % 3, kc = col / 3;
            const int tap = kc % 9, c = kc / 9;
            lwb[(tap * PO + p * 3 + o) * 64 + c] = f2bf(a + b2[col]);
        }
    } else {
        __shared__ short tl[64][72];         // [w][c], +8 pad vs bank stride
        const int bb = b - 112;
        const int wt = bb % 3;
        const int h  = (bb / 3) % HH;
        const int n  = bb / (3 * HH);
        const int w0 = wt * 64;
        // read: 1024 float4s; consecutive threads -> consecutive 16B in a row
#pragma unroll
        for (int i = 0; i < 4; ++i) {
            const int idx = i * 256 + t;     // 0..1023
            const int c   = idx >> 4;        // channel 0..63
            const int j4  = idx & 15;        // float4 within 64 w
            const float4 v = *(const float4*)
                &x[(((size_t)(n * 64 + c)) * HH + h) * WWD + w0 + j4 * 4];
            tl[j4 * 4 + 0][c] = f2bf(v.x);
            tl[j4 * 4 + 1][c] = f2bf(v.y);
            tl[j4 * 4 + 2][c] = f2bf(v.z);
            tl[j4 * 4 + 3][c] = f2bf(v.w);
        }
        __syncthreads();
        // write: 32B/thread, 8KB fully contiguous per block
        const int w  = t >> 2;
        const int c0 = (t & 3) * 16;
        short* dst = &xt[(((size_t)n * HH + h) * WWD + w0 + w) * 64 + c0];
        *(bf16x8*)&dst[0] = *(const bf16x8*)&tl[w][c0];
        *(bf16x8*)&dst[8] = *(const bf16x8*)&tl[w][c0 + 8];
    }
}

// ---------------- Stage B: MFMA dynamic conv (reads NHWC bf16) --------------
__global__ __launch_bounds__(192, 3) void meta_up_mfma(
        const short* __restrict__ xt, const short* __restrict__ lwb,
        float* __restrict__ out) {
    __shared__ __align__(16) short smem[3 * 66 * 64];   // 25,344 B
    short* xlds = smem;                    // [r][j][c], c in XOR'd 16B blocks
    float* obuf = (float*)smem;            // reused post-MFMA: 12 x 260 floats

    // XCD-band swizzle: 2304 strips = 8 XCDs x 288; contiguous (n,h) per XCD.
    const int strip = (blockIdx.x & 7) * 288 + (blockIdx.x >> 3);
    const int n   = strip / (HH * 3);
    const int rem = strip % (HH * 3);
    const int h   = rem / 3;
    const int wch = rem % 3;
    const int w0  = wch * 64;

    const int tid  = threadIdx.x;
    const int lane = tid & 63, wv = tid >> 6;     // wv = staging row AND po-tile
    const int quad = lane >> 4, l15 = lane & 15;

    // B fragments: one po-tile (16 po) per wave, all 9 taps x 2 K-chunks.
    bf16x8 Bfrag[18];
#pragma unroll
    for (int tap = 0; tap < 9; ++tap)
#pragma unroll
        for (int kc2 = 0; kc2 < 2; ++kc2)
            Bfrag[tap * 2 + kc2] = *(const bf16x8*)
                &lwb[(tap * PO + wv * 16 + l15) * 64 + kc2 * 32 + quad * 8];
#pragma unroll
    for (int i = 0; i < 18; ++i) pin(Bfrag[i]);

    // Stage row gr = h+wv-1 from NHWC bf16: row = 66 cols x 64ch = 8448 B.
    // Chunk q in [0,528): j = q>>3, cb = q&7 -> 16B contiguous load; lanes
    // cover 1KB contiguous per iteration. Loads all issued before writes.
    {
        const int gr  = h + wv - 1;
        const bool rok = (unsigned)gr < (unsigned)HH;
        const short* __restrict__ src_row =
            xt + (size_t)(n * HH + (rok ? gr : 0)) * (WWD * 64);
        const bf16x8 z = {0, 0, 0, 0, 0, 0, 0, 0};
        bf16x8 vv[8];
#pragma unroll
        for (int i = 0; i < 8; ++i) {
            const int q  = i * 64 + lane;          // 0..511 -> j 0..63
            const int j  = q >> 3, cb = q & 7;
            const int gc = w0 - 1 + j;             // only j=0 can be OOB here
            const bool ok = rok && ((unsigned)gc < (unsigned)WWD);
            vv[i] = ok ? *(const bf16x8*)&src_row[(size_t)(ok ? gc : 0) * 64 + cb * 8]
                       : z;
        }
#pragma unroll
        for (int i = 0; i < 8; ++i) {
            const int q = i * 64 + lane;
            const int j = q >> 3, cb = q & 7;
            *(bf16x8*)&xlds[(wv * 66 + j) * 64 + ((cb ^ (j & 7)) << 3)] = vv[i];
        }
        if (lane < 16) {                           // tail: j = 64, 65
            const int q  = 512 + lane;
            const int j  = q >> 3, cb = q & 7;
            const int gc = w0 - 1 + j;             // j=65 OOB when w0=128
            const bool ok = rok && ((unsigned)gc < (unsigned)WWD);
            const bf16x8 v = ok ?
                *(const bf16x8*)&src_row[(size_t)(ok ? gc : 0) * 64 + cb * 8] : z;
            *(bf16x8*)&xlds[(wv * 66 + j) * 64 + ((cb ^ (j & 7)) << 3)] = v;
        }
    }
    __syncthreads();

    // Main loop: FULLY unrolled 9 taps x 2 K-chunks x 4 m-tiles = 72 MFMAs.
    f32x4 acc[4];
#pragma unroll
    for (int mt = 0; mt < 4; ++mt) acc[mt] = (f32x4){0.f, 0.f, 0.f, 0.f};

#pragma unroll
    for (int tap = 0; tap < 9; ++tap) {
        const int di = tap / 3, dj = tap % 3;
#pragma unroll
        for (int kc2 = 0; kc2 < 2; ++kc2) {
            const bf16x8 b = Bfrag[tap * 2 + kc2];
#pragma unroll
            for (int mt = 0; mt < 4; ++mt) {
                const int col = mt * 16 + l15 + dj;           // 0..65
                const int blk = (kc2 * 4 + quad) ^ (col & 7);
                bf16x8 a = *(const bf16x8*)&xlds[(di * 66 + col) * 64 + (blk << 3)];
                acc[mt] = __builtin_amdgcn_mfma_f32_16x16x32_bf16(a, b, acc[mt], 0, 0, 0);
            }
        }
    }

    // Epilogue: transpose D through LDS -> full-line coalesced stores.
    __syncthreads();                       // all xlds reads complete
    {
        const int po = wv * 16 + l15;
        const int o  = po % 3;
        const int p  = po / 3;
        const int si = p >> 2, sj = p & 3;
        const int osi = o * 4 + si;
#pragma unroll
        for (int mt = 0; mt < 4; ++mt)
#pragma unroll
            for (int r4 = 0; r4 < 4; ++r4) {
                const int wl = mt * 16 + quad * 4 + r4;
                obuf[osi * 260 + wl * 4 + sj] = acc[mt][r4];
            }
    }
    __syncthreads();
    {
        const int osi = tid >> 4;          // 0..11
        const int c16 = tid & 15;
        const int o = osi >> 2, si = osi & 3;
        const size_t base =
            ((size_t)(n * OC + o) * (SS * HH) + (size_t)(SS * h + si)) * (SS * WWD)
            + (size_t)(4 * w0) + c16 * 16;
        const float* __restrict__ src = &obuf[osi * 260 + c16 * 16];
#pragma unroll
        for (int i = 0; i < 4; ++i)        // 64B contiguous per thread
            *(float4*)&out[base + i * 4] = *(const float4*)&src[i * 4];
    }
}

extern "C" void kernel_launch(void* const* d_in, const int* in_sizes, int n_in,
                              void* d_out, int out_size, void* d_ws, size_t ws_size,
                              hipStream_t stream) {
    const float* x  = (const float*)d_in[0];
    const float* W1 = (const float*)d_in[1];
    const float* b1 = (const float*)d_in[2];
    const float* W2 = (const float*)d_in[3];
    const float* b2 = (const float*)d_in[4];
    float* out = (float*)d_out;
    short* lwb = (short*)d_ws;                  // 27,648 bf16 = 55 KB
    short* xt  = (short*)d_ws + 32768;          // NHWC bf16 x, 18.9 MB

    prep_kernel<<<112 + 4 * HH * 3, 256, 0, stream>>>(x, W1, b1, W2, b2, lwb, xt);
    meta_up_mfma<<<4 * HH * 3, 192, 0, stream>>>(xt, lwb, out);
}

// Round 3
// 118.161 us; speedup vs baseline: 1.0867x; 1.0298x over previous
//
#include <hip/hip_runtime.h>

// MetaUpSampler via bf16 MFMA — round 10 (= R9 resubmit; R9 bench was an
// infra flake: "container failed twice" at acquire, no validation result).
// R8 counters: meta fell below the 43us harness fill (top-5 = all fills),
//   dur only -6.7us -> meta ~35-40us, still latency-bound far above its
//   ~8us HBM floor. Waste: each block made ONE h-row (rows staged 3x,
//   1 ds_read per MFMA, 2304 blocks in ~3 residency rounds at 31% occ).
// R9/R10 fix: HB=3 output rows per block. 768 blocks = exactly 3/CU, ALL
//   co-resident (one round). 5 staged rows serve 3 outputs (1.67 rows/h).
//   Loop order (dj,kc)->mt->r->di reuses each A fragment over up to 3 di:
//   120 ds_read_b128 per 216 MFMAs (was 216/216). B via 2-deep rolling
//   prefetch Bb[2][3] (24 VGPR live; R6 lesson: pinning all 18 + acc>4
//   spills). acc[3][4] = 48 VGPR; total ~130-150 < 168 cap at 3 waves/EU.
// Workspace layout: lwb @ 0 (55KB), xt @ +64KB (18.9MB).

#define HH   192
#define WWD  192
#define SS   4
#define OC   3
#define PO   48
#define HID  256
#define W2LD 1728

typedef short  bf16x8 __attribute__((ext_vector_type(8)));
typedef float  f32x4  __attribute__((ext_vector_type(4)));

static __device__ __forceinline__ short f2bf(float f) {
    unsigned u = __float_as_uint(f);
    unsigned r = (u + 0x7fffu + ((u >> 16) & 1u)) >> 16;   // RNE
    return (short)r;
}

static __device__ __forceinline__ void pin(bf16x8& v) {
    asm volatile("" : "+v"(v));    // force VGPR residency; block load sinking
}

// ---------------- Stage A (fused): MLP -> weights  +  x -> NHWC bf16 -------
// Blocks 0..111: lw MLP (flattened (7,16) grid). Blocks 112..2415: transpose
// one (n,h,64w) tile of x from NCHW f32 to NHWC bf16 via an LDS tile.
__global__ __launch_bounds__(256) void prep_kernel(
        const float* __restrict__ x,
        const float* __restrict__ W1, const float* __restrict__ b1,
        const float* __restrict__ W2, const float* __restrict__ b2,
        short* __restrict__ lwb, short* __restrict__ xt) {
    const int b = blockIdx.x;
    const int t = threadIdx.x;
    if (b < 112) {
        __shared__ float hlds[HID];
        const int p = b / 7;
        {
            const float pi = (float)(p >> 2) * 0.25f;
            const float pj = (float)(p & 3) * 0.25f;
            const float v = 0.25f * W1[t] + pi * W1[HID + t] + pj * W1[2 * HID + t]
                          + b1[t];
            hlds[t] = v > 0.f ? v : 0.f;
        }
        __syncthreads();
        const int col = (b % 7) * 256 + t;   // 0..1791 (guard at 1728)
        if (col < W2LD) {
            float a = 0.f;
#pragma unroll 32
            for (int hh = 0; hh < HID; ++hh)
                a += hlds[hh] * W2[hh * W2LD + col];   // coalesced 4B + LDS bcast
            const int o = col % 3, kc = col / 3;
            const int tap = kc % 9, c = kc / 9;
            lwb[(tap * PO + p * 3 + o) * 64 + c] = f2bf(a + b2[col]);
        }
    } else {
        __shared__ short tl[64][72];         // [w][c], +8 pad vs bank stride
        const int bb = b - 112;
        const int wt = bb % 3;
        const int h  = (bb / 3) % HH;
        const int n  = bb / (3 * HH);
        const int w0 = wt * 64;
        // read: 1024 float4s; consecutive threads -> consecutive 16B in a row
#pragma unroll
        for (int i = 0; i < 4; ++i) {
            const int idx = i * 256 + t;     // 0..1023
            const int c   = idx >> 4;        // channel 0..63
            const int j4  = idx & 15;        // float4 within 64 w
            const float4 v = *(const float4*)
                &x[(((size_t)(n * 64 + c)) * HH + h) * WWD + w0 + j4 * 4];
            tl[j4 * 4 + 0][c] = f2bf(v.x);
            tl[j4 * 4 + 1][c] = f2bf(v.y);
            tl[j4 * 4 + 2][c] = f2bf(v.z);
            tl[j4 * 4 + 3][c] = f2bf(v.w);
        }
        __syncthreads();
        // write: 32B/thread, 8KB fully contiguous per block
        const int w  = t >> 2;
        const int c0 = (t & 3) * 16;
        short* dst = &xt[(((size_t)n * HH + h) * WWD + w0 + w) * 64 + c0];
        *(bf16x8*)&dst[0] = *(const bf16x8*)&tl[w][c0];
        *(bf16x8*)&dst[8] = *(const bf16x8*)&tl[w][c0 + 8];
    }
}

// ---------------- Stage B: MFMA dynamic conv, 3 h-rows per block -----------
__global__ __launch_bounds__(192, 3) void meta_up_mfma(
        const short* __restrict__ xt, const short* __restrict__ lwb,
        float* __restrict__ out) {
    __shared__ __align__(16) short smem[5 * 66 * 64];   // 42,240 B
    short* xlds = smem;                    // [r][j][c], c in XOR'd 16B blocks
    float* obuf = (float*)smem;            // reused post-MFMA: 36 x 260 floats

    // XCD-contiguous mapping: 768 blocks = 8 XCDs x 96; per XCD contiguous
    // (n,wch,hg) range -> xt working set ~2.4MB, fits the 4MB XCD L2.
    const int g   = (blockIdx.x & 7) * 96 + (blockIdx.x >> 3);
    const int n   = g / 192;
    const int rem = g % 192;
    const int wch = rem / 64;
    const int hg  = rem % 64;
    const int h0  = hg * 3;
    const int w0  = wch * 64;

    const int tid  = threadIdx.x;
    const int lane = tid & 63, wv = tid >> 6;     // wv = po-tile (16 po each)
    const int quad = lane >> 4, l15 = lane & 15;

    // Stage 5 rows (gr = h0-1 .. h0+3): wave wv does r = wv and wv+3.
    // Row = 66 cols x 64 ch bf16 = 8448 B; 16B contiguous chunks per lane.
    {
        const bf16x8 z = {0, 0, 0, 0, 0, 0, 0, 0};
#pragma unroll
        for (int r0 = 0; r0 < 2; ++r0) {
            const int r = wv + r0 * 3;
            if (r >= 5) break;                       // wave 2 stages one row
            const int gr  = h0 - 1 + r;
            const bool rok = (unsigned)gr < (unsigned)HH;
            const short* __restrict__ src_row =
                xt + (size_t)(n * HH + (rok ? gr : 0)) * (WWD * 64);
            bf16x8 vv[8];
#pragma unroll
            for (int i = 0; i < 8; ++i) {
                const int q  = i * 64 + lane;        // 0..511 -> j 0..63
                const int j  = q >> 3, cb = q & 7;
                const int gc = w0 - 1 + j;
                const bool ok = rok && ((unsigned)gc < (unsigned)WWD);
                vv[i] = ok ?
                    *(const bf16x8*)&src_row[(size_t)(ok ? gc : 0) * 64 + cb * 8] : z;
            }
#pragma unroll
            for (int i = 0; i < 8; ++i) {
                const int q = i * 64 + lane;
                const int j = q >> 3, cb = q & 7;
                *(bf16x8*)&xlds[(r * 66 + j) * 64 + ((cb ^ (j & 7)) << 3)] = vv[i];
            }
            if (lane < 16) {                         // tail: j = 64, 65
                const int q  = 512 + lane;
                const int j  = q >> 3, cb = q & 7;
                const int gc = w0 - 1 + j;
                const bool ok = rok && ((unsigned)gc < (unsigned)WWD);
                const bf16x8 v = ok ?
                    *(const bf16x8*)&src_row[(size_t)(ok ? gc : 0) * 64 + cb * 8] : z;
                *(bf16x8*)&xlds[(r * 66 + j) * 64 + ((cb ^ (j & 7)) << 3)] = v;
            }
        }
    }
    __syncthreads();

    // MFMA: 6 (dj,kc) phases x 4 mt x 5 r; A fragment (r,col,kc) reused for
    // up to 3 di (output rows ih = r - di). 120 ds_reads, 216 MFMAs / wave.
    f32x4 acc[3][4];
#pragma unroll
    for (int ih = 0; ih < 3; ++ih)
#pragma unroll
        for (int mt = 0; mt < 4; ++mt) acc[ih][mt] = (f32x4){0.f, 0.f, 0.f, 0.f};

    bf16x8 Bb[2][3];
#pragma unroll
    for (int di = 0; di < 3; ++di) {                 // preload phase 0 (dj=0,kc=0)
        Bb[0][di] = *(const bf16x8*)
            &lwb[((di * 3 + 0) * PO + wv * 16 + l15) * 64 + 0 * 32 + quad * 8];
        pin(Bb[0][di]);
    }

#pragma unroll
    for (int b = 0; b < 6; ++b) {
        const int dj = b >> 1, kc2 = b & 1;
        if (b < 5) {                                 // rolling B prefetch
            const int djn = (b + 1) >> 1, kcn = (b + 1) & 1;
#pragma unroll
            for (int di = 0; di < 3; ++di) {
                Bb[(b + 1) & 1][di] = *(const bf16x8*)
                    &lwb[((di * 3 + djn) * PO + wv * 16 + l15) * 64 + kcn * 32 + quad * 8];
                pin(Bb[(b + 1) & 1][di]);
            }
        }
#pragma unroll
        for (int mt = 0; mt < 4; ++mt) {
            const int col = mt * 16 + l15 + dj;      // 0..65
            const int blk = (kc2 * 4 + quad) ^ (col & 7);
#pragma unroll
            for (int r = 0; r < 5; ++r) {
                bf16x8 a = *(const bf16x8*)&xlds[(r * 66 + col) * 64 + (blk << 3)];
#pragma unroll
                for (int di = 0; di < 3; ++di) {
                    const int ih = r - di;
                    if (ih >= 0 && ih < 3)
                        acc[ih][mt] = __builtin_amdgcn_mfma_f32_16x16x32_bf16(
                            a, Bb[b & 1][di], acc[ih][mt], 0, 0, 0);
                }
            }
        }
    }

    // Epilogue: transpose D through LDS -> full-line coalesced stores (x3 h).
    __syncthreads();                       // all xlds reads complete
    {
        const int po = wv * 16 + l15;
        const int o  = po % 3;
        const int p  = po / 3;
        const int si = p >> 2, sj = p & 3;
        const int osi = o * 4 + si;
#pragma unroll
        for (int ih = 0; ih < 3; ++ih)
#pragma unroll
            for (int mt = 0; mt < 4; ++mt)
#pragma unroll
                for (int r4 = 0; r4 < 4; ++r4) {
                    const int wl = mt * 16 + quad * 4 + r4;
                    obuf[(ih * 12 + osi) * 260 + wl * 4 + sj] = acc[ih][mt][r4];
                }
    }
    __syncthreads();
    {
        const int osi = tid >> 4;          // 0..11
        const int c16 = tid & 15;
        const int o = osi >> 2, si = osi & 3;
#pragma unroll
        for (int ih = 0; ih < 3; ++ih) {
            const int hh = h0 + ih;
            const size_t base =
                ((size_t)(n * OC + o) * (SS * HH) + (size_t)(SS * hh + si)) * (SS * WWD)
                + (size_t)(4 * w0) + c16 * 16;
            const float* __restrict__ src = &obuf[(ih * 12 + osi) * 260 + c16 * 16];
#pragma unroll
            for (int i = 0; i < 4; ++i)    // 64B contiguous per thread
                *(float4*)&out[base + i * 4] = *(const float4*)&src[i * 4];
        }
    }
}

extern "C" void kernel_launch(void* const* d_in, const int* in_sizes, int n_in,
                              void* d_out, int out_size, void* d_ws, size_t ws_size,
                              hipStream_t stream) {
    const float* x  = (const float*)d_in[0];
    const float* W1 = (const float*)d_in[1];
    const float* b1 = (const float*)d_in[2];
    const float* W2 = (const float*)d_in[3];
    const float* b2 = (const float*)d_in[4];
    float* out = (float*)d_out;
    short* lwb = (short*)d_ws;                  // 27,648 bf16 = 55 KB
    short* xt  = (short*)d_ws + 32768;          // NHWC bf16 x, 18.9 MB

    prep_kernel<<<112 + 4 * HH * 3, 256, 0, stream>>>(x, W1, b1, W2, b2, lwb, xt);
    meta_up_mfma<<<768, 192, 0, stream>>>(xt, lwb, out);
}